// Round 6
// baseline (2847.255 us; speedup 1.0000x reference)
//
#include <hip/hip_runtime.h>

// ---------------- problem constants ----------------
#define TPB   256
#define NWG   256
#define SEQL  200
#define BATCH 64
#define EDIM  300
#define HDIM  512
#define ODIM  5
#define NROW  (4*HDIM)   // 2048 gate rows

// ---------------- persist-kernel LDS layout (word offsets) ----------------
// region0 [0..32768): h_T swizzled [512][64] in 4 chunks of 8192 words
//   (DMA target) / embT[300][64] (fallback) / ex[8][64][17] overlay (8704 w)
#define CHUNK    8192                    // 128 k-rows x 64 = 32 KB
#define EX_BSTR  17
#define EX_RSTR  (64*EX_BSTR)            // 1088
#define WIH_OFF  32768                   // fallback W_ih rows [8][304]
#define WIH_STR  304
#define LDS_WORDS (WIH_OFF + 8*WIH_STR)  // 35200 words
#define LDS_BYTES (LDS_WORDS*4)          // 140800 B (<160 KiB, forces 1 wg/CU)

#define HBUF_WORDS (BATCH*HDIM)          // 32768 floats = 128 KiB / buffer
#define HBUF_BYTES (HBUF_WORDS*4)

// ---------------- precompute-kernel LDS ----------------
#define ESTR 308
#define PRE_LDS_BYTES (BATCH * ESTR * 4) // 78848 B

#define GATES_FLOATS ((size_t)SEQL * NROW * BATCH)   // 104.9 MB

__device__ __forceinline__ float fast_sigmoid(float x) {
    return 1.0f / (1.0f + __expf(-x));
}
__device__ __forceinline__ float fast_tanh(float x) {
    return 2.0f / (1.0f + __expf(-2.0f * x)) - 1.0f;
}

// 16B global -> LDS DMA (no VGPR round trip)
__device__ __forceinline__ void gll16(const float* g, float* l) {
#if __has_builtin(__builtin_amdgcn_global_load_lds)
    __builtin_amdgcn_global_load_lds(
        (const __attribute__((address_space(1))) unsigned int*)g,
        (__attribute__((address_space(3))) unsigned int*)l, 16, 0, 0);
#else
    *(float4*)l = *(const float4*)g;
#endif
}

// counted vmcnt + sched fence (rule #18); raw barrier (no auto vmcnt(0) drain)
#define WAITVM(n) do { asm volatile("s_waitcnt vmcnt(" #n ")" ::: "memory"); \
                       __builtin_amdgcn_sched_barrier(0); } while (0)
#define KBAR()    do { __builtin_amdgcn_s_barrier(); \
                       __builtin_amdgcn_sched_barrier(0); } while (0)

// ============================================================================
// Precompute: gates[s][row][b] = (x_s @ W_ih^T)[b][row]   (no bias)
// ============================================================================
extern "C" __global__ void __launch_bounds__(256, 1)
lstm_pre(const int* __restrict__ x, const float* __restrict__ emb,
         const float* __restrict__ W_ih, float* __restrict__ gates)
{
    extern __shared__ float embs[];
    const int tid = threadIdx.x;
    const int s   = blockIdx.x >> 3;
    const int rb  = blockIdx.x & 7;

    for (int i = tid; i < BATCH * 75; i += 256) {
        int b = i / 75, j = i - b * 75;
        int row = x[b * SEQL + s];
        float4 v = ((const float4*)(emb + (size_t)row * EDIM))[j];
        *(float4*)&embs[b * ESTR + 4 * j] = v;
    }
    __syncthreads();

    const int bi = tid >> 5;
    const int ri = tid & 31;
    const int row0 = rb * 256 + ri * 8;
    const float* wp = W_ih + (size_t)row0 * EDIM;

    float acc[8][8];
#pragma unroll
    for (int a = 0; a < 8; a++)
#pragma unroll
        for (int b = 0; b < 8; b++) acc[a][b] = 0.0f;

    for (int t2 = 0; t2 < 75; t2++) {
        float4 w[8], e[8];
#pragma unroll
        for (int rr = 0; rr < 8; rr++)
            w[rr] = *(const float4*)(wp + rr * EDIM + 4 * t2);
#pragma unroll
        for (int bb = 0; bb < 8; bb++)
            e[bb] = *(const float4*)&embs[(bi * 8 + bb) * ESTR + 4 * t2];
#pragma unroll
        for (int rr = 0; rr < 8; rr++)
#pragma unroll
            for (int bb = 0; bb < 8; bb++) {
                acc[rr][bb] = fmaf(w[rr].x, e[bb].x, acc[rr][bb]);
                acc[rr][bb] = fmaf(w[rr].y, e[bb].y, acc[rr][bb]);
                acc[rr][bb] = fmaf(w[rr].z, e[bb].z, acc[rr][bb]);
                acc[rr][bb] = fmaf(w[rr].w, e[bb].w, acc[rr][bb]);
            }
    }
#pragma unroll
    for (int rr = 0; rr < 8; rr++) {
        float* dst = gates + ((size_t)s * NROW + row0 + rr) * BATCH + bi * 8;
        *(float4*)dst       = make_float4(acc[rr][0], acc[rr][1], acc[rr][2], acc[rr][3]);
        *(float4*)(dst + 4) = make_float4(acc[rr][4], acc[rr][5], acc[rr][6], acc[rr][7]);
    }
}

// ============================================================================
// Persistent LSTM. Roles: bo = tid&7, rg = (tid>>3)&1 (rows 4rg..4rg+3),
// kh = tid>>4 (k-offset). Thread's k-set: {c*128 + kh*8 + j : c<4, j<8} so
// ALL threads compute on EVERY k-chunk -> chunked DMA/compute pipeline with
// counted vmcnt. h stored SWIZZLED: word(k,b) = k*64 + ((b + 4*((k>>3)&3))&63)
// -> pass-B reads drop from 8-way to 4-way bank aliasing; DMA stays linear.
// ============================================================================
extern "C" __global__ void __launch_bounds__(TPB, 1)
lstm_persist(const int* __restrict__ x, const float* __restrict__ emb,
             const float* __restrict__ W_ih, const float* __restrict__ W_hh,
             const float* __restrict__ b_ih, const float* __restrict__ b_hh,
             const float* __restrict__ gates,   // may be null
             float* __restrict__ hrot,          // rot_n buffers of [512][64]
             int rot_n,
             unsigned int* __restrict__ flags)  // [256], memset 0 per launch
{
    extern __shared__ float lds[];
    const int tid = threadIdx.x;
    const int wg  = blockIdx.x;
    const bool pre = (gates != nullptr);

    const int bo = tid & 7;
    const int rg = (tid >> 3) & 1;
    const int kh = tid >> 4;                 // 0..15

    // ---- W_hh -> 128 VGPRs: rows 4rg..4rg+3; k = c*128 + kh*8 + 4u+i ----
    float4 w4[4][4][2];
#pragma unroll
    for (int c = 0; c < 4; c++)
#pragma unroll
        for (int p = 0; p < 4; p++) {
            const int r = 4 * rg + p;
            const size_t R = (size_t)((r >> 1) * HDIM + 2 * wg + (r & 1));
            const float* wp = W_hh + R * HDIM + c * 128 + kh * 8;
            w4[c][p][0] = *(const float4*)(wp);
            w4[c][p][1] = *(const float4*)(wp + 4);
        }

    if (!pre) {
        for (int i = tid; i < 8 * EDIM; i += TPB) {
            int r = i / EDIM, e = i - r * EDIM;
            int R = ((r >> 1) << 9) + 2 * wg + (r & 1);
            lds[WIH_OFF + r * WIH_STR + e] = W_ih[(size_t)R * EDIM + e];
        }
    }

    // cell role: tid<128 owns (hi, cb)
    const int hi = (tid >> 6) & 1;
    const int cb = tid & 63;
    float bias4[4];
#pragma unroll
    for (int g = 0; g < 4; g++) {
        int R = g * HDIM + 2 * wg + hi;
        bias4[g] = b_ih[R] + b_hh[R];
    }
    float c_reg = 0.0f;

    // pass-B read columns (swizzle rot = 4*((k>>3)&3) = 4*(kh&3))
    const int rot  = 4 * (kh & 3);
    const int col0 = (8 * bo + rot) & 63;
    const int col1 = (8 * bo + 4 + rot) & 63;
    // store-side rotation: row k=2wg+hi -> (k>>3)&3 = (wg>>2)&3
    const int scol = (cb + 4 * ((wg >> 2) & 3)) & 63;

    int rbuf = 0, wbuf = 1;
    __syncthreads();

#define DMA_CHUNK(c) do { _Pragma("unroll")                                     \
    for (int u = 0; u < 8; u++)                                                 \
        gll16(hs + (c) * CHUNK + 4 * (tid + 256 * u),                           \
              &lds[(c) * CHUNK + 4 * (tid + 256 * u)]); } while (0)

#define COMPUTE(c) do { _Pragma("unroll")                                       \
    for (int j = 0; j < 8; j++) {                                               \
        const int kw = ((c) * 128 + kh * 8 + j) * 64;                           \
        float4 h0 = *(const float4*)&lds[kw + col0];                            \
        float4 h1 = *(const float4*)&lds[kw + col1];                            \
        _Pragma("unroll")                                                       \
        for (int p = 0; p < 4; p++) {                                           \
            const float4 wv = w4[(c)][p][j >> 2];                               \
            const float wc = (j & 3) == 0 ? wv.x : (j & 3) == 1 ? wv.y          \
                           : (j & 3) == 2 ? wv.z : wv.w;                        \
            acc[p][0] = fmaf(wc, h0.x, acc[p][0]);                              \
            acc[p][1] = fmaf(wc, h0.y, acc[p][1]);                              \
            acc[p][2] = fmaf(wc, h0.z, acc[p][2]);                              \
            acc[p][3] = fmaf(wc, h0.w, acc[p][3]);                              \
            acc[p][4] = fmaf(wc, h1.x, acc[p][4]);                              \
            acc[p][5] = fmaf(wc, h1.y, acc[p][5]);                              \
            acc[p][6] = fmaf(wc, h1.z, acc[p][6]);                              \
            acc[p][7] = fmaf(wc, h1.w, acc[p][7]);                              \
        } } } while (0)

    for (int s = 0; s < SEQL; s++) {
        // ---- (0) prefetch this step's input-proj gates (hidden under poll) ----
        float gp[4] = {0.f, 0.f, 0.f, 0.f};
        if (pre && tid < 128) {
#pragma unroll
            for (int g = 0; g < 4; g++)
                gp[g] = gates[((size_t)s * NROW + g * HDIM + 2 * wg + hi) * BATCH + cb];
        }

        float acc[4][8];
#pragma unroll
        for (int p = 0; p < 4; p++)
#pragma unroll
            for (int j = 0; j < 8; j++) acc[p][j] = 0.f;

        // ---- (1) fallback pass A (region0 embT, unswizzled; pre never runs this) ----
        if (!pre) {
            for (int i = tid; i < BATCH * 75; i += TPB) {
                int b = i / 75, j = i - b * 75;
                int row = x[b * SEQL + s];
                float4 v = *(const float4*)(emb + (size_t)row * EDIM + 4 * j);
                lds[(4 * j + 0) * 64 + b] = v.x;
                lds[(4 * j + 1) * 64 + b] = v.y;
                lds[(4 * j + 2) * 64 + b] = v.z;
                lds[(4 * j + 3) * 64 + b] = v.w;
            }
            __syncthreads();
            const int nkq = (kh < 4) ? 16 : ((kh == 4) ? 11 : 0);
            const float* eb = &lds[kh * 4096 + 8 * bo];
            for (int kq = 0; kq < nkq; kq++) {
                float4 wv[4];
#pragma unroll
                for (int p = 0; p < 4; p++)
                    wv[p] = *(const float4*)&lds[WIH_OFF + (4 * rg + p) * WIH_STR + kh * 64 + 4 * kq];
                float4 h0[4], h1[4];
#pragma unroll
                for (int dk = 0; dk < 4; dk++) {
                    h0[dk] = *(const float4*)(eb + (4 * kq + dk) * 64);
                    h1[dk] = *(const float4*)(eb + (4 * kq + dk) * 64 + 4);
                }
#pragma unroll
                for (int p = 0; p < 4; p++) {
#pragma unroll
                    for (int dk = 0; dk < 4; dk++) {
                        float wc = dk == 0 ? wv[p].x : dk == 1 ? wv[p].y : dk == 2 ? wv[p].z : wv[p].w;
                        acc[p][0] = fmaf(wc, h0[dk].x, acc[p][0]);
                        acc[p][1] = fmaf(wc, h0[dk].y, acc[p][1]);
                        acc[p][2] = fmaf(wc, h0[dk].z, acc[p][2]);
                        acc[p][3] = fmaf(wc, h0[dk].w, acc[p][3]);
                        acc[p][4] = fmaf(wc, h1[dk].x, acc[p][4]);
                        acc[p][5] = fmaf(wc, h1[dk].y, acc[p][5]);
                        acc[p][6] = fmaf(wc, h1[dk].z, acc[p][6]);
                        acc[p][7] = fmaf(wc, h1[dk].w, acc[p][7]);
                    }
                }
            }
            __syncthreads();   // embT reads done before ex-overlay writes
        }

        if (s) {
            // ---- (2) device barrier: all wgs finished step s-1 ----
            if (tid < 64) {
                const unsigned tgt = (unsigned)s;
                for (;;) {
                    unsigned f0 = __hip_atomic_load(flags + tid,       __ATOMIC_RELAXED, __HIP_MEMORY_SCOPE_AGENT);
                    unsigned f1 = __hip_atomic_load(flags + tid + 64,  __ATOMIC_RELAXED, __HIP_MEMORY_SCOPE_AGENT);
                    unsigned f2 = __hip_atomic_load(flags + tid + 128, __ATOMIC_RELAXED, __HIP_MEMORY_SCOPE_AGENT);
                    unsigned f3 = __hip_atomic_load(flags + tid + 192, __ATOMIC_RELAXED, __HIP_MEMORY_SCOPE_AGENT);
                    if (f0 >= tgt && f1 >= tgt && f2 >= tgt && f3 >= tgt) break;
                    __builtin_amdgcn_s_sleep(1);
                }
                __builtin_amdgcn_fence(__ATOMIC_ACQUIRE, "agent");  // L1+L2 inv
            }
            __syncthreads();

            // ---- (3)+(4) chunked DMA || pass-B pipeline (counted vmcnt) ----
            const float* hs = hrot + (size_t)rbuf * HBUF_WORDS;
            DMA_CHUNK(0);
            DMA_CHUNK(1); WAITVM(8); KBAR(); COMPUTE(0);
            DMA_CHUNK(2); WAITVM(8); KBAR(); COMPUTE(1);
            DMA_CHUNK(3); WAITVM(8); KBAR(); COMPUTE(2);
                          WAITVM(0); KBAR(); COMPUTE(3);
            // ex region (words < 8704) is chunks 0-1: all waves are past the
            // last KBAR -> chunk 0/1 reads complete; chunk-3 readers untouched.
        }

        // ---- (5) exchange k-partials: ex[row][b][17] ----
#pragma unroll
        for (int p = 0; p < 4; p++) {
            const int r = 4 * rg + p;
#pragma unroll
            for (int j = 0; j < 8; j++)
                lds[r * EX_RSTR + (8 * bo + j) * EX_BSTR + kh] = acc[p][j];
        }
        __syncthreads();

        // ---- (6) cell update (tid<128 owns (hi, cb)) ----
        if (tid < 128) {
            float gs[4];
#pragma unroll
            for (int g = 0; g < 4; g++) {
                float sum = bias4[g] + gp[g];
#pragma unroll
                for (int kk = 0; kk < 16; kk++)
                    sum += lds[(2 * g + hi) * EX_RSTR + cb * EX_BSTR + kk];
                gs[g] = sum;
            }
            float iv = fast_sigmoid(gs[0]);
            float fv = fast_sigmoid(gs[1]);
            float gv = fast_tanh(gs[2]);
            float ov = fast_sigmoid(gs[3]);
            c_reg = fv * c_reg + iv * gv;
            float hv = ov * fast_tanh(c_reg);
            // swizzled contiguous 512B block: word (2wg+hi)*64 + scol
            unsigned int* hw = (unsigned int*)(hrot + (size_t)wbuf * HBUF_WORDS);
            __hip_atomic_store(hw + 128 * wg + 64 * hi + scol, __float_as_uint(hv),
                               __ATOMIC_RELAXED, __HIP_MEMORY_SCOPE_AGENT);
        }
        __syncthreads();   // all h stores drained (vmcnt 0) before flag release

        if (tid == 0)
            __hip_atomic_store(flags + wg, (unsigned)(s + 1),
                               __ATOMIC_RELEASE, __HIP_MEMORY_SCOPE_AGENT);

        rbuf = wbuf;
        wbuf = (wbuf + 1 == rot_n) ? 0 : wbuf + 1;
    }
#undef DMA_CHUNK
#undef COMPUTE
}

// FC head + softmax over SWIZZLED h_T[512][64]
extern "C" __global__ void __launch_bounds__(320)
lstm_epilogue(const float* __restrict__ hT, const float* __restrict__ W_fc,
              const float* __restrict__ b_fc, float* __restrict__ out)
{
    __shared__ float sl[ODIM * BATCH];
    const int t = threadIdx.x;
    {
        int o = t / BATCH, b = t - o * BATCH;
        float acc = b_fc[o];
        const float4* wv = (const float4*)(W_fc + o * HDIM);
#pragma unroll 8
        for (int k4 = 0; k4 < HDIM / 4; k4++) {
            float4 w = wv[k4];
            const int k0 = 4 * k4;
            const int bs = (b + 4 * ((k0 >> 3) & 3)) & 63;   // same for k0..k0+3
            acc = fmaf(hT[(k0 + 0) * BATCH + bs], w.x, acc);
            acc = fmaf(hT[(k0 + 1) * BATCH + bs], w.y, acc);
            acc = fmaf(hT[(k0 + 2) * BATCH + bs], w.z, acc);
            acc = fmaf(hT[(k0 + 3) * BATCH + bs], w.w, acc);
        }
        sl[o * BATCH + b] = acc;
    }
    __syncthreads();
    if (t < BATCH) {
        float l0 = sl[t], l1 = sl[BATCH + t], l2 = sl[2 * BATCH + t];
        float l3 = sl[3 * BATCH + t], l4 = sl[4 * BATCH + t];
        float m = fmaxf(fmaxf(fmaxf(l0, l1), fmaxf(l2, l3)), l4);
        float e0 = __expf(l0 - m), e1 = __expf(l1 - m), e2 = __expf(l2 - m);
        float e3 = __expf(l3 - m), e4 = __expf(l4 - m);
        float inv = 1.0f / (e0 + e1 + e2 + e3 + e4);
        out[t * ODIM + 0] = e0 * inv;
        out[t * ODIM + 1] = e1 * inv;
        out[t * ODIM + 2] = e2 * inv;
        out[t * ODIM + 3] = e3 * inv;
        out[t * ODIM + 4] = e4 * inv;
    }
}

extern "C" void kernel_launch(void* const* d_in, const int* in_sizes, int n_in,
                              void* d_out, int out_size, void* d_ws, size_t ws_size,
                              hipStream_t stream)
{
    const int*   x    = (const int*)d_in[0];
    const float* emb  = (const float*)d_in[1];
    const float* W_ih = (const float*)d_in[2];
    const float* W_hh = (const float*)d_in[3];
    const float* b_ih = (const float*)d_in[4];
    const float* b_hh = (const float*)d_in[5];
    const float* W_fc = (const float*)d_in[6];
    const float* b_fc = (const float*)d_in[7];
    float* out = (float*)d_out;

    // ws layout: [flags 1KB][gates (optional)][rotating h buffers]
    unsigned int* flags = (unsigned int*)d_ws;
    char* p = (char*)d_ws + 1024;
    size_t remain = (ws_size > 1024) ? ws_size - 1024 : 0;
    const size_t gates_bytes = GATES_FLOATS * sizeof(float);
    float* gates = nullptr;
    if (remain >= gates_bytes + 2 * (size_t)HBUF_BYTES) {
        gates = (float*)p;
        p += gates_bytes;
        remain -= gates_bytes;
    }
    int rot_n = (int)(remain / HBUF_BYTES);
    if (rot_n > SEQL + 1) rot_n = SEQL + 1;
    if (rot_n < 2) rot_n = 2;
    float* hrot = (float*)p;

    (void)hipMemsetAsync(flags, 0, 1024, stream);

    (void)hipFuncSetAttribute((const void*)lstm_persist,
                              hipFuncAttributeMaxDynamicSharedMemorySize, LDS_BYTES);
    if (gates) {
        (void)hipFuncSetAttribute((const void*)lstm_pre,
                                  hipFuncAttributeMaxDynamicSharedMemorySize, PRE_LDS_BYTES);
        lstm_pre<<<SEQL * 8, 256, PRE_LDS_BYTES, stream>>>(x, emb, W_ih, gates);
    }

    lstm_persist<<<NWG, TPB, LDS_BYTES, stream>>>(x, emb, W_ih, W_hh, b_ih, b_hh,
                                                  gates, hrot, rot_n, flags);

    const int fin = SEQL % rot_n;   // buffer written at step SEQL-1
    lstm_epilogue<<<1, 320, 0, stream>>>(hrot + (size_t)fin * HBUF_WORDS,
                                         W_fc, b_fc, out);
}